// Round 3
// baseline (798.193 us; speedup 1.0000x reference)
//
#include <hip/hip_runtime.h>

#define IN_DIM 512
#define OUT_DIM 16
#define KC 32
#define TILE_ROWS 256

// ---------------------------------------------------------------------------
// h' = dinv ⊙ (x @ W)   (dinv==nullptr -> plain x@W)
// x staged through LDS in 256x32 tiles (pad +1). W loads wave-uniform.
// ---------------------------------------------------------------------------
__global__ __launch_bounds__(256) void gemm_xw(const float* __restrict__ x,
                                               const float* __restrict__ W,
                                               const float* __restrict__ dinv,
                                               float* __restrict__ h, int n) {
    __shared__ float xs[TILE_ROWS * (KC + 1)];
    const int tid = threadIdx.x;
    const int rbase = blockIdx.x * TILE_ROWS;
    const int myrow = rbase + tid;

    float acc[OUT_DIM];
#pragma unroll
    for (int j = 0; j < OUT_DIM; ++j) acc[j] = 0.f;

    for (int kc = 0; kc < IN_DIM; kc += KC) {
        __syncthreads();
#pragma unroll
        for (int i = 0; i < 8; ++i) {
            const int v = tid + 256 * i;
            const int r = v >> 3;
            const int c = (v & 7) << 2;
            if (rbase + r < n) {
                const float4 f = *(const float4*)(x + (size_t)(rbase + r) * IN_DIM + kc + c);
                float* d = xs + r * (KC + 1) + c;
                d[0] = f.x; d[1] = f.y; d[2] = f.z; d[3] = f.w;
            }
        }
        __syncthreads();

        const float* xrow = xs + tid * (KC + 1);
#pragma unroll 4
        for (int k = 0; k < KC; ++k) {
            const float xv = xrow[k];
            const float* wr = W + (size_t)(kc + k) * OUT_DIM;
            const float4 w0 = *(const float4*)(wr + 0);
            const float4 w1 = *(const float4*)(wr + 4);
            const float4 w2 = *(const float4*)(wr + 8);
            const float4 w3 = *(const float4*)(wr + 12);
            acc[0]  += xv * w0.x; acc[1]  += xv * w0.y; acc[2]  += xv * w0.z; acc[3]  += xv * w0.w;
            acc[4]  += xv * w1.x; acc[5]  += xv * w1.y; acc[6]  += xv * w1.z; acc[7]  += xv * w1.w;
            acc[8]  += xv * w2.x; acc[9]  += xv * w2.y; acc[10] += xv * w2.z; acc[11] += xv * w2.w;
            acc[12] += xv * w3.x; acc[13] += xv * w3.y; acc[14] += xv * w3.z; acc[15] += xv * w3.w;
        }
    }

    if (myrow < n) {
        float s = dinv ? dinv[myrow] : 1.0f;
        float4* op = (float4*)(h + (size_t)myrow * OUT_DIM);
        op[0] = make_float4(s*acc[0],  s*acc[1],  s*acc[2],  s*acc[3]);
        op[1] = make_float4(s*acc[4],  s*acc[5],  s*acc[6],  s*acc[7]);
        op[2] = make_float4(s*acc[8],  s*acc[9],  s*acc[10], s*acc[11]);
        op[3] = make_float4(s*acc[12], s*acc[13], s*acc[14], s*acc[15]);
    }
}

// ---------------- CSR build: histogram + scan ------------------------------

__global__ void hist_dst(const int* __restrict__ dst, int* __restrict__ hist, int E) {
    const int e = blockIdx.x * 256 + threadIdx.x;
    if (e < E) atomicAdd(&hist[dst[e]], 1);
}

// partial[b] = sum of hist[b*256 .. b*256+255]
__global__ void block_sum(const int* __restrict__ hist, int* __restrict__ partial, int n) {
    __shared__ int s[256];
    const int tid = threadIdx.x;
    const int i = blockIdx.x * 256 + tid;
    s[tid] = (i < n) ? hist[i] : 0;
    __syncthreads();
    for (int off = 128; off > 0; off >>= 1) {
        if (tid < off) s[tid] += s[tid + off];
        __syncthreads();
    }
    if (tid == 0) partial[blockIdx.x] = s[0];
}

// single block: exclusive scan of partial[0..B)
__global__ void scan_partial(int* __restrict__ partial, int B) {
    __shared__ int s[512];
    const int tid = threadIdx.x;
    const int v = (tid < B) ? partial[tid] : 0;
    s[tid] = v;
    __syncthreads();
    for (int off = 1; off < 512; off <<= 1) {
        int t = (tid >= off) ? s[tid - off] : 0;
        __syncthreads();
        s[tid] += t;
        __syncthreads();
    }
    if (tid < B) partial[tid] = s[tid] - v;  // exclusive
}

// row_ptr[i] = partial[blk] + excl-scan-in-block(hist); cursor=row_ptr; dinv=rsqrt(hist+1)
__global__ void scan_final(const int* __restrict__ hist, const int* __restrict__ partial,
                           int* __restrict__ row_ptr, int* __restrict__ cursor,
                           float* __restrict__ dinv, int n, int E) {
    __shared__ int s[256];
    const int tid = threadIdx.x;
    const int i = blockIdx.x * 256 + tid;
    const int v = (i < n) ? hist[i] : 0;
    s[tid] = v;
    __syncthreads();
    for (int off = 1; off < 256; off <<= 1) {
        int t = (tid >= off) ? s[tid - off] : 0;
        __syncthreads();
        s[tid] += t;
        __syncthreads();
    }
    if (i < n) {
        const int excl = partial[blockIdx.x] + s[tid] - v;
        row_ptr[i] = excl;
        cursor[i] = excl;
        dinv[i] = rsqrtf((float)(v + 1));
    }
    if (i == 0) row_ptr[n] = E;
}

// scatter src ids into dst-sorted order
__global__ void edge_bin(const int* __restrict__ ei, int* __restrict__ cursor,
                         int* __restrict__ sorted_src, int E) {
    const int e = blockIdx.x * 256 + threadIdx.x;
    if (e < E) {
        const int src = ei[e];
        const int dst = ei[(size_t)E + e];
        const int p = atomicAdd(&cursor[dst], 1);
        sorted_src[p] = src;
    }
}

// out[d][j] = dinv[d] * (h'[d][j] + sum_{s in CSR[d]} h'[s][j]) + b[j]
// 16 lanes per node; 4-way unrolled independent gathers for MLP.
__global__ __launch_bounds__(256) void aggregate(const int* __restrict__ row_ptr,
                                                 const int* __restrict__ sorted_src,
                                                 const float* __restrict__ hp,
                                                 const float* __restrict__ dinv,
                                                 const float* __restrict__ b,
                                                 float* __restrict__ out, int n) {
    const int t = blockIdx.x * 256 + threadIdx.x;
    const int node = t >> 4;
    if (node >= n) return;
    const int j = t & 15;

    const int beg = row_ptr[node];
    const int end = row_ptr[node + 1];

    float acc = hp[(size_t)node * OUT_DIM + j];  // self-loop term
    int e = beg;
    for (; e + 4 <= end; e += 4) {
        const int s0 = sorted_src[e];
        const int s1 = sorted_src[e + 1];
        const int s2 = sorted_src[e + 2];
        const int s3 = sorted_src[e + 3];
        const float v0 = hp[(size_t)s0 * OUT_DIM + j];
        const float v1 = hp[(size_t)s1 * OUT_DIM + j];
        const float v2 = hp[(size_t)s2 * OUT_DIM + j];
        const float v3 = hp[(size_t)s3 * OUT_DIM + j];
        acc += v0 + v1 + v2 + v3;
    }
    for (; e < end; ++e) acc += hp[(size_t)sorted_src[e] * OUT_DIM + j];

    out[(size_t)node * OUT_DIM + j] = dinv[node] * acc + b[j];
}

// ---------------- fallback (R2 atomic path) --------------------------------

__global__ void deg_init(float* __restrict__ deg, int n) {
    const int i = blockIdx.x * 256 + threadIdx.x;
    if (i < n) deg[i] = 1.0f;
}
__global__ void deg_count(const int* __restrict__ col, float* __restrict__ deg, int E) {
    const int e = blockIdx.x * 256 + threadIdx.x;
    if (e < E) atomicAdd(&deg[col[e]], 1.0f);
}
__global__ void dinv_out_init(const float* __restrict__ deg, float* __restrict__ dinv,
                              const float* __restrict__ h, const float* __restrict__ b,
                              float* __restrict__ out, int n) {
    const int gid = blockIdx.x * 256 + threadIdx.x;
    if (gid >= n * OUT_DIM) return;
    const int i = gid >> 4;
    const int j = gid & 15;
    const float di = rsqrtf(deg[i]);
    if (j == 0) dinv[i] = di;
    out[gid] = di * di * h[gid] + b[j];
}
__global__ __launch_bounds__(256) void edge_scatter(const int* __restrict__ ei,
                                                    const float* __restrict__ dinv,
                                                    const float* __restrict__ h,
                                                    float* __restrict__ out, int E) {
    const int t = blockIdx.x * 256 + threadIdx.x;
    const int e = t >> 4;
    if (e >= E) return;
    const int j = t & 15;
    const int src = ei[e];
    const int dst = ei[(size_t)E + e];
    const float a = dinv[src] * dinv[dst];
    atomicAdd(&out[(size_t)dst * OUT_DIM + j], a * h[(size_t)src * OUT_DIM + j]);
}

// ---------------------------------------------------------------------------

extern "C" void kernel_launch(void* const* d_in, const int* in_sizes, int n_in,
                              void* d_out, int out_size, void* d_ws, size_t ws_size,
                              hipStream_t stream) {
    const float* x  = (const float*)d_in[0];
    const int*   ei = (const int*)d_in[1];   // int inputs delivered as int32
    const float* W  = (const float*)d_in[2];
    const float* b  = (const float*)d_in[3];
    float* out = (float*)d_out;

    const int n = in_sizes[0] / IN_DIM;   // 100000
    const int E = in_sizes[1] / 2;        // 3200000
    const int B = (n + 255) / 256;        // 391 scan blocks

    // CSR-path workspace layout
    float* hp       = (float*)d_ws;                 // n*16
    int*   hist     = (int*)(hp + (size_t)n * OUT_DIM);  // n
    int*   row_ptr  = hist + n;                     // n+1
    int*   cursor   = row_ptr + n + 1;              // n
    float* dinv     = (float*)(cursor + n);         // n
    int*   partial  = (int*)(dinv + n);             // pad to 1024
    int*   sorted   = partial + 1024;               // E
    const size_t need = ((size_t)n * OUT_DIM + 4 * (size_t)n + 1 + 1024 + (size_t)E) * 4;

    if (ws_size >= need && B <= 512) {
        hipMemsetAsync(hist, 0, (size_t)n * sizeof(int), stream);
        hist_dst<<<(E + 255) / 256, 256, 0, stream>>>(ei + E, hist, E);
        block_sum<<<B, 256, 0, stream>>>(hist, partial, n);
        scan_partial<<<1, 512, 0, stream>>>(partial, B);
        scan_final<<<B, 256, 0, stream>>>(hist, partial, row_ptr, cursor, dinv, n, E);
        gemm_xw<<<(n + TILE_ROWS - 1) / TILE_ROWS, 256, 0, stream>>>(x, W, dinv, hp, n);
        edge_bin<<<(E + 255) / 256, 256, 0, stream>>>(ei, cursor, sorted, E);
        aggregate<<<(n * 16 + 255) / 256, 256, 0, stream>>>(row_ptr, sorted, hp, dinv, b, out, n);
    } else {
        // fallback: R2 atomic path (needs ~7.2 MB)
        float* h    = (float*)d_ws;
        float* deg  = h + (size_t)n * OUT_DIM;
        float* dv   = deg + n;
        gemm_xw<<<(n + TILE_ROWS - 1) / TILE_ROWS, 256, 0, stream>>>(x, W, nullptr, h, n);
        deg_init<<<(n + 255) / 256, 256, 0, stream>>>(deg, n);
        deg_count<<<(E + 255) / 256, 256, 0, stream>>>(ei + E, deg, E);
        dinv_out_init<<<((n * OUT_DIM) + 255) / 256, 256, 0, stream>>>(deg, dv, h, b, out, n);
        const long long st = (long long)E * OUT_DIM;
        edge_scatter<<<(int)((st + 255) / 256), 256, 0, stream>>>(ei, dv, h, out, E);
    }
}

// Round 4
// 643.256 us; speedup vs baseline: 1.2409x; 1.2409x over previous
//
#include <hip/hip_runtime.h>
#include <hip/hip_fp16.h>

#define IN_DIM 512
#define OUT_DIM 16
#define KC 32
#define TILE_ROWS 256

// ---------------------------------------------------------------------------
// h' = dinv ⊙ (x @ W)  : fp32 vector GEMM, x via LDS 256x32 tiles (pad +1,
// 2-way bank alias = free). W loads are wave-uniform -> scalar path.
// ---------------------------------------------------------------------------
__global__ __launch_bounds__(256) void gemm_xw(const float* __restrict__ x,
                                               const float* __restrict__ W,
                                               const float* __restrict__ dinv,
                                               float* __restrict__ hp, int n) {
    __shared__ float xs[TILE_ROWS * (KC + 1)];
    const int tid = threadIdx.x;
    const int rbase = blockIdx.x * TILE_ROWS;
    const int myrow = rbase + tid;

    float acc[OUT_DIM];
#pragma unroll
    for (int j = 0; j < OUT_DIM; ++j) acc[j] = 0.f;

    for (int kc = 0; kc < IN_DIM; kc += KC) {
        __syncthreads();
#pragma unroll
        for (int i = 0; i < 8; ++i) {
            const int v = tid + 256 * i;
            const int r = v >> 3;
            const int c = (v & 7) << 2;
            if (rbase + r < n) {
                const float4 f = *(const float4*)(x + (size_t)(rbase + r) * IN_DIM + kc + c);
                float* d = xs + r * (KC + 1) + c;
                d[0] = f.x; d[1] = f.y; d[2] = f.z; d[3] = f.w;
            }
        }
        __syncthreads();

        const float* xrow = xs + tid * (KC + 1);
#pragma unroll 4
        for (int k = 0; k < KC; ++k) {
            const float xv = xrow[k];
            const float* wr = W + (size_t)(kc + k) * OUT_DIM;  // uniform -> s_load
            const float4 w0 = *(const float4*)(wr + 0);
            const float4 w1 = *(const float4*)(wr + 4);
            const float4 w2 = *(const float4*)(wr + 8);
            const float4 w3 = *(const float4*)(wr + 12);
            acc[0]  += xv * w0.x; acc[1]  += xv * w0.y; acc[2]  += xv * w0.z; acc[3]  += xv * w0.w;
            acc[4]  += xv * w1.x; acc[5]  += xv * w1.y; acc[6]  += xv * w1.z; acc[7]  += xv * w1.w;
            acc[8]  += xv * w2.x; acc[9]  += xv * w2.y; acc[10] += xv * w2.z; acc[11] += xv * w2.w;
            acc[12] += xv * w3.x; acc[13] += xv * w3.y; acc[14] += xv * w3.z; acc[15] += xv * w3.w;
        }
    }

    if (myrow < n) {
        const float s = dinv[myrow];
        float4* op = (float4*)(hp + (size_t)myrow * OUT_DIM);
        op[0] = make_float4(s*acc[0],  s*acc[1],  s*acc[2],  s*acc[3]);
        op[1] = make_float4(s*acc[4],  s*acc[5],  s*acc[6],  s*acc[7]);
        op[2] = make_float4(s*acc[8],  s*acc[9],  s*acc[10], s*acc[11]);
        op[3] = make_float4(s*acc[12], s*acc[13], s*acc[14], s*acc[15]);
    }
}

// degree histogram over targets (int atomics into 400 KB, L2-resident)
__global__ void hist_dst(const int* __restrict__ dst, int* __restrict__ hist, int E) {
    const int e = blockIdx.x * 256 + threadIdx.x;
    if (e < E) atomicAdd(&hist[dst[e]], 1);
}

// dinv[i] = rsqrt(deg_in + self-loop)
__global__ void dinv_k(const int* __restrict__ hist, float* __restrict__ dinv, int n) {
    const int i = blockIdx.x * 256 + threadIdx.x;
    if (i < n) dinv[i] = rsqrtf((float)(hist[i] + 1));
}

// per edge (src->dst): acc16[dst][:] += fp16(h'[src][:])
// 8 lanes/edge: 64B coalesced h' gather, 32B packed-fp16 atomic.
__global__ __launch_bounds__(256) void scatter_f16(const int* __restrict__ ei,
                                                   const float* __restrict__ hp,
                                                   __half2* __restrict__ acc, int E) {
    const long long gid = (long long)blockIdx.x * 256 + threadIdx.x;
    const int e = (int)(gid >> 3);
    if (e >= E) return;
    const int j2 = (int)(gid & 7);
    const int src = ei[e];
    const int dst = ei[(size_t)E + e];
    const float2 v = ((const float2*)(hp + (size_t)src * OUT_DIM))[j2];
    unsafeAtomicAdd(&acc[(size_t)dst * 8 + j2], __floats2half2_rn(v.x, v.y));
}

// out[d][j] = dinv[d] * (acc16[d][j] + h'[d][j]) + b[j]
__global__ void finalize(const __half* __restrict__ acc, const float* __restrict__ hp,
                         const float* __restrict__ dinv, const float* __restrict__ b,
                         float* __restrict__ out, int n) {
    const int gid = blockIdx.x * 256 + threadIdx.x;
    if (gid >= n * OUT_DIM) return;
    const int i = gid >> 4;
    const int j = gid & 15;
    out[gid] = dinv[i] * (__half2float(acc[gid]) + hp[gid]) + b[j];
}

// ---------------------------------------------------------------------------

extern "C" void kernel_launch(void* const* d_in, const int* in_sizes, int n_in,
                              void* d_out, int out_size, void* d_ws, size_t ws_size,
                              hipStream_t stream) {
    const float* x  = (const float*)d_in[0];
    const int*   ei = (const int*)d_in[1];   // int inputs delivered as int32
    const float* W  = (const float*)d_in[2];
    const float* b  = (const float*)d_in[3];
    float* out = (float*)d_out;

    const int n = in_sizes[0] / IN_DIM;   // 100000
    const int E = in_sizes[1] / 2;        // 3200000

    // ws layout: h' [n*16 f32] | hist [n i32] | dinv [n f32] | acc16 [n*16 f16]
    float*   hp   = (float*)d_ws;
    int*     hist = (int*)(hp + (size_t)n * OUT_DIM);
    float*   dinv = (float*)(hist + n);
    __half*  acc  = (__half*)(dinv + n);
    // total ≈ 10.4 MB; R3's 21.3 MB path ran, so ws_size suffices.

    hipMemsetAsync(hist, 0, (size_t)n * sizeof(int), stream);
    hipMemsetAsync(acc, 0, (size_t)n * OUT_DIM * sizeof(__half), stream);

    hist_dst<<<(E + 255) / 256, 256, 0, stream>>>(ei + E, hist, E);
    dinv_k<<<(n + 255) / 256, 256, 0, stream>>>(hist, dinv, n);

    gemm_xw<<<(n + TILE_ROWS - 1) / TILE_ROWS, 256, 0, stream>>>(x, W, dinv, hp, n);

    const long long st = (long long)E * 8;
    scatter_f16<<<(int)((st + 255) / 256), 256, 0, stream>>>(ei, hp, (__half2*)acc, E);

    finalize<<<(n * OUT_DIM + 255) / 256, 256, 0, stream>>>(acc, hp, dinv, b, out, n);
}